// Round 8
// baseline (66.776 us; speedup 1.0000x reference)
//
#include <hip/hip_runtime.h>
#include <math.h>

#define BS 4096
#define D 128
#define NC 512
#define NS 8           // column slices
#define SC 512         // cols per slice
#define MARGINF 0.1f
#define NEGV -1e30f
#define BIGD 1e30f
#define LSTR 12        // floats per (row,slice) record: dV[0..3]@0, {dV4,sV4,pad,pad}@4, sV[0..3]@8

typedef float f32x4 __attribute__((ext_vector_type(4)));
typedef short s16x8 __attribute__((ext_vector_type(8)));

__device__ __forceinline__ unsigned short f2bf(float f) {
    unsigned int u = __float_as_uint(f);
    unsigned int r = u + 0x7FFFu + ((u >> 16) & 1u);
    return (unsigned short)(r >> 16);
}

// sorted-ascending top-5 insert via med3: W[0]=min(V0,v), W[t]=med3(V[t-1],V[t],v).
// 5 INDEPENDENT ops (v_min + 4x v_med3) -- no serial chain within the insert.
__device__ __forceinline__ void insV(float v, float (&V)[5]) {
    float w0 = fminf(V[0], v);
    float w1 = __builtin_amdgcn_fmed3f(V[0], V[1], v);
    float w2 = __builtin_amdgcn_fmed3f(V[1], V[2], v);
    float w3 = __builtin_amdgcn_fmed3f(V[2], V[3], v);
    float w4 = __builtin_amdgcn_fmed3f(V[3], V[4], v);
    V[0] = w0; V[1] = w1; V[2] = w2; V[3] = w3; V[4] = w4;
}

// descending insert with same-class flag payload (epilogue only, 5 uses/row)
__device__ __forceinline__ void insDF(float v, int f, float (&V)[5], int (&F)[5]) {
#pragma unroll
    for (int t = 0; t < 5; ++t) {
        bool c = v > V[t];
        float tv = V[t]; int tf = F[t];
        V[t] = c ? v : tv; F[t] = c ? f : tf;
        v = c ? tv : v;    f = c ? tf : f;
    }
}

// norms + class histogram + fragment-tiled bf16 copy of X (LDS-staged transpose,
// both global sides coalesced; LDS XOR-swizzled 16B chunks => <=2-way banks).
// Xp layout: row group g=row>>4, k-chunk ks, lane l2=(q*16+rl):
//   byte off = g*4096 + ks*1024 + l2*16 holds row (16g+rl), k [ks*32+q*8, +8)
__global__ __launch_bounds__(256) void prep_kernel(
        const float* __restrict__ X, const int* __restrict__ labels,
        float* __restrict__ norms, int* __restrict__ counts,
        unsigned short* __restrict__ Xp) {
    __shared__ __align__(16) unsigned short sb[32 * 128];   // 8 KB
    const int t = threadIdx.x, bx = blockIdx.x;
    const int row0 = bx * 32;

#pragma unroll
    for (int i = 0; i < 4; ++i) {
        int idx = i * 256 + t;                 // float4 units 0..1023
        int lr = idx >> 5, kq = idx & 31;
        float4 v = ((const float4*)X)[(size_t)row0 * 32 + idx];
        float acc = v.x * v.x + v.y * v.y + v.z * v.z + v.w * v.w;
#pragma unroll
        for (int off = 1; off < 32; off <<= 1) acc += __shfl_xor(acc, off);
        if (kq == 0) norms[row0 + lr] = acc;
        ushort4 hv = { f2bf(v.x), f2bf(v.y), f2bf(v.z), f2bf(v.w) };
        int chunk = (kq >> 1) ^ (lr & 7);
        *(ushort4*)((char*)sb + lr * 256 + (chunk << 4) + (kq & 1) * 8) = hv;
    }
    if (t < 32) atomicAdd(&counts[labels[row0 + t]], 1);
    __syncthreads();

#pragma unroll
    for (int i = 0; i < 2; ++i) {
        int u = i * 256 + t;                   // 16B units 0..511
        int j = u >> 8, ug = u & 255;
        int ks = ug >> 6, l2 = ug & 63;
        int lr = j * 16 + (l2 & 15), q = l2 >> 4;
        int chunk = (ks * 4 + q) ^ (lr & 7);
        ulonglong2 d = *(const ulonglong2*)((const char*)sb + lr * 256 + (chunk << 4));
        *(ulonglong2*)((char*)Xp + (size_t)(bx * 2 + j) * 4096 + ks * 1024 + l2 * 16) = d;
    }
}

// wave = 16 rows x 512 cols (one slice), processed as 4 sub-slices of 128.
// No LDS, coalesced 1KB fragment loads. Swapped MFMA: lane (rl=l&15, q=l>>4)
// holds cols {i*16+q*4+e} of row rl. Values-only top-5 in d2' = nC - 2s space.
__global__ __launch_bounds__(256, 8) void main_kernel(
        const unsigned short* __restrict__ Xp, const int* __restrict__ labels,
        const float* __restrict__ norms, float* __restrict__ lists) {
    const int t = threadIdx.x, bx = blockIdx.x;
    const int slice = bx & (NS - 1);
    const int col0 = slice * SC;
    const int w = t >> 6, l = t & 63, rl = l & 15, q = l >> 4;
    const int gRow = (bx >> 3) * 4 + w;
    const int rowG = gRow * 16 + rl;
    const int lR = labels[rowG];
    const char* Pb = (const char*)Xp;

    s16x8 brow[4];
#pragma unroll
    for (int ks = 0; ks < 4; ++ks)
        brow[ks] = *(const s16x8*)(Pb + (size_t)gRow * 4096 + ks * 1024 + l * 16);

    float dV[5], sV[5];
#pragma unroll
    for (int i = 0; i < 5; ++i) { dV[i] = BIGD; sV[i] = BIGD; }

#pragma unroll 1
    for (int cg = 0; cg < 4; ++cg) {
        f32x4 acc[8];
#pragma unroll
        for (int i = 0; i < 8; ++i) acc[i] = (f32x4){0.f, 0.f, 0.f, 0.f};

#pragma unroll
        for (int ks = 0; ks < 4; ++ks) {
            s16x8 af[8];
#pragma unroll
            for (int i = 0; i < 8; ++i)
                af[i] = *(const s16x8*)(Pb + (size_t)(slice * 32 + cg * 8 + i) * 4096 + ks * 1024 + l * 16);
#pragma unroll
            for (int i = 0; i < 8; ++i)
                acc[i] = __builtin_amdgcn_mfma_f32_16x16x32_bf16(af[i], brow[ks], acc[i], 0, 0, 0);
        }

#pragma unroll
        for (int i = 0; i < 8; ++i) {
            f32x4 nc4 = *(const f32x4*)(norms + col0 + cg * 128 + i * 16 + q * 4);
            int4  lc4 = *(const int4*)(labels + col0 + cg * 128 + i * 16 + q * 4);
            int lcv[4] = {lc4.x, lc4.y, lc4.z, lc4.w};
#pragma unroll
            for (int e = 0; e < 4; ++e) {
                float v = fmaf(acc[i][e], -2.f, nc4[e]);   // d2' = nC - 2s (nR added at merge)
                bool same = (lcv[e] == lR);
                insV(same ? BIGD : v, dV);
                if (__any(same)) insV(same ? v : BIGD, sV);
            }
        }
    }

    // merge the 4 col-quarters of each row (lanes l, l^16, l^32, l^48)
#pragma unroll
    for (int off = 16; off <= 32; off <<= 1) {
        float bv[5];
#pragma unroll
        for (int i = 0; i < 5; ++i) bv[i] = __shfl_xor(dV[i], off);
#pragma unroll
        for (int i = 0; i < 5; ++i) insV(bv[i], dV);
#pragma unroll
        for (int i = 0; i < 5; ++i) bv[i] = __shfl_xor(sV[i], off);
#pragma unroll
        for (int i = 0; i < 5; ++i) insV(bv[i], sV);
    }

    if (q == 0) {
        float* Lp = lists + ((size_t)rowG * NS + slice) * LSTR;
        *(f32x4*)Lp       = (f32x4){dV[0], dV[1], dV[2], dV[3]};
        *(f32x4*)(Lp + 4) = (f32x4){dV[4], sV[4], 0.f, 0.f};
        *(f32x4*)(Lp + 8) = (f32x4){sV[0], sV[1], sV[2], sV[3]};
    }
}

// 8 threads per row: thread part owns slice `part` (both diff & same lists).
// shfl-merge across xor 1,2,4; epilogue on part==0; block partial summed;
// last block (ticket) sums the 128 partials in fixed order -> out.
__global__ __launch_bounds__(256) void merge_kernel(
        const float* __restrict__ lists, const int* __restrict__ counts,
        const int* __restrict__ labels, const float* __restrict__ norms,
        float* __restrict__ partials, int* __restrict__ ticket,
        float* __restrict__ out) {
    __shared__ float sh[256];
    const int t = threadIdx.x, bx = blockIdx.x;
    const int gid = bx * 256 + t;
    const int r = gid >> 3, part = gid & 7;

    const float* rec = lists + (size_t)(r * NS + part) * LSTR;
    f32x4 a = *(const f32x4*)rec;
    f32x4 b = *(const f32x4*)(rec + 4);
    f32x4 c = *(const f32x4*)(rec + 8);
    float dV[5] = {a.x, a.y, a.z, a.w, b.x};
    float sV[5] = {c.x, c.y, c.z, c.w, b.y};

#pragma unroll
    for (int off = 1; off <= 4; off <<= 1) {
        float bv[5];
#pragma unroll
        for (int i = 0; i < 5; ++i) bv[i] = __shfl_xor(dV[i], off);
#pragma unroll
        for (int i = 0; i < 5; ++i) insV(bv[i], dV);
#pragma unroll
        for (int i = 0; i < 5; ++i) bv[i] = __shfl_xor(sV[i], off);
#pragma unroll
        for (int i = 0; i < 5; ++i) insV(bv[i], sV);
    }

    float res = 0.f;
    if (part == 0) {
        const float nR = norms[r];
        const int pos = counts[labels[r]];
        const int ks = (pos < 5) ? pos : 5;
        float dS[5], sS[5];
#pragma unroll
        for (int i = 0; i < 5; ++i) {
            float dv = dV[i]; bool ok = dv < 1e29f;
            dS[i] = ok ? (-sqrtf(fmaxf(nR + dv, 0.f)) + MARGINF) : NEGV;
        }
#pragma unroll
        for (int i = 0; i < 5; ++i) {
            float sv = sV[i]; bool ok = sv < 1e29f;
            sS[i] = ok ? -sqrtf(fmaxf(nR + sv, 0.f)) : NEGV;
        }
        float mV[5]; int mF[5];
#pragma unroll
        for (int i = 0; i < 5; ++i) { mV[i] = dS[i]; mF[i] = 0; }
#pragma unroll
        for (int i = 0; i < 5; ++i) insDF(sS[i], 1, mV, mF);

        float fpsum = 0.f; int fpn = 0;
#pragma unroll
        for (int i = 0; i < 5; ++i)
            if (i < ks && mF[i] == 0) { fpsum += mV[i]; fpn++; }
        const int s0 = ks - fpn;
        float fnsum = 0.f;
#pragma unroll
        for (int i = 0; i < 5; ++i)
            if (i >= s0 && i < s0 + fpn) fnsum += sS[i];
        res = fpsum - fnsum;
    }
    sh[t] = res;
    __syncthreads();
    for (int s = 128; s > 0; s >>= 1) {
        if (t < s) sh[t] += sh[t + s];
        __syncthreads();
    }
    if (t == 0) {
        partials[bx] = sh[0];
        __threadfence();
        int old = atomicAdd(ticket, 1);
        if (old == (int)gridDim.x - 1) {
            __threadfence();
            float s = 0.f;
            for (int i = 0; i < (int)gridDim.x; ++i) s += partials[i];
            out[0] = s;
        }
    }
}

extern "C" void kernel_launch(void* const* d_in, const int* in_sizes, int n_in,
                              void* d_out, int out_size, void* d_ws, size_t ws_size,
                              hipStream_t stream) {
    const float* X      = (const float*)d_in[0];
    const int*   labels = (const int*)d_in[1];

    float* ws       = (float*)d_ws;
    float* norms    = ws;                          // 4096 f32
    float* partials = ws + BS;                     // 128 f32
    int*   counts   = (int*)(ws + BS + 128);       // 512 i32
    int*   ticket   = counts + NC;                 // 1 i32 (+pad to 16)
    float* lists    = ws + BS + 128 + NC + 16;     // 4096*8*12 f32 = 1.57 MB
    unsigned short* Xp = (unsigned short*)(lists + (size_t)BS * NS * LSTR); // 1 MB

    hipMemsetAsync(counts, 0, (NC + 16) * sizeof(int), stream);
    prep_kernel<<<BS / 32, 256, 0, stream>>>(X, labels, norms, counts, Xp);
    main_kernel<<<(BS / 64) * NS, 256, 0, stream>>>(Xp, labels, norms, lists);
    merge_kernel<<<(BS * 8) / 256, 256, 0, stream>>>(lists, counts, labels, norms,
                                                     partials, ticket, (float*)d_out);
}

// Round 9
// 42.743 us; speedup vs baseline: 1.5623x; 1.5623x over previous
//
#include <hip/hip_runtime.h>
#include <math.h>

#define BS 4096
#define D 128
#define NS 32          // column slices
#define SC 128         // cols per slice
#define MARGINF 0.1f
#define NEGV -1e30f
#define BIGD 1e30f
#define LSTR 12        // record: dV[0..3]@0, {dV4,sV4,cnt,pad}@4, sV[0..3]@8

typedef float f32x4 __attribute__((ext_vector_type(4)));
typedef short s16x8 __attribute__((ext_vector_type(8)));

__device__ __forceinline__ unsigned short f2bf(float f) {
    unsigned int u = __float_as_uint(f);
    unsigned int r = u + 0x7FFFu + ((u >> 16) & 1u);
    return (unsigned short)(r >> 16);
}

// sorted-ascending top-5 insert via med3: W[0]=min(V0,v), W[t]=med3(V[t-1],V[t],v).
// 5 INDEPENDENT ops (v_min + 4x v_med3) -- no serial chain within the insert.
__device__ __forceinline__ void insV(float v, float (&V)[5]) {
    float w0 = fminf(V[0], v);
    float w1 = __builtin_amdgcn_fmed3f(V[0], V[1], v);
    float w2 = __builtin_amdgcn_fmed3f(V[1], V[2], v);
    float w3 = __builtin_amdgcn_fmed3f(V[2], V[3], v);
    float w4 = __builtin_amdgcn_fmed3f(V[3], V[4], v);
    V[0] = w0; V[1] = w1; V[2] = w2; V[3] = w3; V[4] = w4;
}

// descending insert with same-class flag payload (epilogue only, 5 uses/row)
__device__ __forceinline__ void insDF(float v, int f, float (&V)[5], int (&F)[5]) {
#pragma unroll
    for (int t = 0; t < 5; ++t) {
        bool c = v > V[t];
        float tv = V[t]; int tf = F[t];
        V[t] = c ? v : tv; F[t] = c ? f : tf;
        v = c ? tv : v;    f = c ? tf : f;
    }
}

// norms + fragment-tiled bf16 copy of X (LDS-staged transpose, both global
// sides coalesced; LDS XOR-swizzled 16B chunks => <=2-way banks). Also zeroes
// the merge ticket (visible to merge via dispatch ordering on the stream).
// Xp layout: row group g=row>>4, k-chunk ks, lane l2=(q*16+rl):
//   byte off = g*4096 + ks*1024 + l2*16 holds row (16g+rl), k [ks*32+q*8, +8)
__global__ __launch_bounds__(256) void prep_kernel(
        const float* __restrict__ X, float* __restrict__ norms,
        unsigned short* __restrict__ Xp, int* __restrict__ ticket) {
    __shared__ __align__(16) unsigned short sb[32 * 128];   // 8 KB
    const int t = threadIdx.x, bx = blockIdx.x;
    const int row0 = bx * 32;

    if (bx == 0 && t == 0) ticket[0] = 0;

#pragma unroll
    for (int i = 0; i < 4; ++i) {
        int idx = i * 256 + t;                 // float4 units 0..1023
        int lr = idx >> 5, kq = idx & 31;
        float4 v = ((const float4*)X)[(size_t)row0 * 32 + idx];
        float acc = v.x * v.x + v.y * v.y + v.z * v.z + v.w * v.w;
#pragma unroll
        for (int off = 1; off < 32; off <<= 1) acc += __shfl_xor(acc, off);
        if (kq == 0) norms[row0 + lr] = acc;
        ushort4 hv = { f2bf(v.x), f2bf(v.y), f2bf(v.z), f2bf(v.w) };
        int chunk = (kq >> 1) ^ (lr & 7);
        *(ushort4*)((char*)sb + lr * 256 + (chunk << 4) + (kq & 1) * 8) = hv;
    }
    __syncthreads();

#pragma unroll
    for (int i = 0; i < 2; ++i) {
        int u = i * 256 + t;                   // 16B units 0..511
        int j = u >> 8, ug = u & 255;
        int ks = ug >> 6, l2 = ug & 63;
        int lr = j * 16 + (l2 & 15), q = l2 >> 4;
        int chunk = (ks * 4 + q) ^ (lr & 7);
        ulonglong2 d = *(const ulonglong2*)((const char*)sb + lr * 256 + (chunk << 4));
        *(ulonglong2*)((char*)Xp + (size_t)(bx * 2 + j) * 4096 + ks * 1024 + l2 * 16) = d;
    }
}

// wave = 16 rows x 128 cols (one slice). No LDS, coalesced 1KB fragment loads.
// Swapped MFMA: lane (rl=l&15, q=l>>4) holds cols {i*16+q*4+e} of row rl.
// Values-only top-5 lists in d2' = nC - 2s space; same-class count per slice.
__global__ __launch_bounds__(256, 8) void main_kernel(
        const unsigned short* __restrict__ Xp, const int* __restrict__ labels,
        const float* __restrict__ norms, float* __restrict__ lists) {
    const int t = threadIdx.x, bx = blockIdx.x;
    const int slice = bx & (NS - 1);
    const int col0 = slice * SC;
    const int w = t >> 6, l = t & 63, rl = l & 15, q = l >> 4;
    const int gRow = (bx >> 5) * 4 + w;
    const int rowG = gRow * 16 + rl;
    const int lR = labels[rowG];
    const char* Pb = (const char*)Xp;

    s16x8 brow[4];
#pragma unroll
    for (int ks = 0; ks < 4; ++ks)
        brow[ks] = *(const s16x8*)(Pb + (size_t)gRow * 4096 + ks * 1024 + l * 16);

    f32x4 acc[8];
#pragma unroll
    for (int i = 0; i < 8; ++i) acc[i] = (f32x4){0.f, 0.f, 0.f, 0.f};

#pragma unroll
    for (int ks = 0; ks < 4; ++ks) {
        s16x8 af[8];
#pragma unroll
        for (int i = 0; i < 8; ++i)
            af[i] = *(const s16x8*)(Pb + (size_t)(slice * 8 + i) * 4096 + ks * 1024 + l * 16);
#pragma unroll
        for (int i = 0; i < 8; ++i)
            acc[i] = __builtin_amdgcn_mfma_f32_16x16x32_bf16(af[i], brow[ks], acc[i], 0, 0, 0);
    }

    float dV[5], sV[5];
#pragma unroll
    for (int i = 0; i < 5; ++i) { dV[i] = BIGD; sV[i] = BIGD; }
    int cnt = 0;

#pragma unroll
    for (int i = 0; i < 8; ++i) {
        f32x4 nc4 = *(const f32x4*)(norms + col0 + i * 16 + q * 4);
        int4  lc4 = *(const int4*)(labels + col0 + i * 16 + q * 4);
        int lcv[4] = {lc4.x, lc4.y, lc4.z, lc4.w};
#pragma unroll
        for (int e = 0; e < 4; ++e) {
            float v = fmaf(acc[i][e], -2.f, nc4[e]);   // d2' = nC - 2s (nR added at merge)
            bool same = (lcv[e] == lR);
            cnt += same ? 1 : 0;
            insV(same ? BIGD : v, dV);
            if (__any(same)) insV(same ? v : BIGD, sV);
        }
    }

    // merge the 4 col-quarters of each row (lanes l, l^16, l^32, l^48)
#pragma unroll
    for (int off = 16; off <= 32; off <<= 1) {
        float bv[5];
#pragma unroll
        for (int i = 0; i < 5; ++i) bv[i] = __shfl_xor(dV[i], off);
#pragma unroll
        for (int i = 0; i < 5; ++i) insV(bv[i], dV);
#pragma unroll
        for (int i = 0; i < 5; ++i) bv[i] = __shfl_xor(sV[i], off);
#pragma unroll
        for (int i = 0; i < 5; ++i) insV(bv[i], sV);
        cnt += __shfl_xor(cnt, off);
    }

    if (q == 0) {
        float* Lp = lists + ((size_t)rowG * NS + slice) * LSTR;
        *(f32x4*)Lp       = (f32x4){dV[0], dV[1], dV[2], dV[3]};
        *(f32x4*)(Lp + 4) = (f32x4){dV[4], sV[4], (float)cnt, 0.f};
        *(f32x4*)(Lp + 8) = (f32x4){sV[0], sV[1], sV[2], sV[3]};
    }
}

// 8 threads per row: thread part owns slices {part*4..part*4+3}.
// shfl-merge xor 1,2,4; epilogue on part==0; block partial; last block
// (ticket) parallel-sums the 128 partials in fixed order -> out.
__global__ __launch_bounds__(256) void merge_kernel(
        const float* __restrict__ lists, const int* __restrict__ labels,
        const float* __restrict__ norms, float* __restrict__ partials,
        int* __restrict__ ticket, float* __restrict__ out) {
    __shared__ float sh[256];
    __shared__ int lastFlag;
    const int t = threadIdx.x, bx = blockIdx.x;
    const int gid = bx * 256 + t;
    const int r = gid >> 3, part = gid & 7;

    float dV[5], sV[5];
#pragma unroll
    for (int i = 0; i < 5; ++i) { dV[i] = BIGD; sV[i] = BIGD; }
    float cntf = 0.f;
#pragma unroll
    for (int s = 0; s < 4; ++s) {
        const float* rec = lists + (size_t)(r * NS + part * 4 + s) * LSTR;
        f32x4 a = *(const f32x4*)rec;
        f32x4 b = *(const f32x4*)(rec + 4);
        f32x4 c = *(const f32x4*)(rec + 8);
        insV(a.x, dV); insV(a.y, dV); insV(a.z, dV); insV(a.w, dV); insV(b.x, dV);
        insV(c.x, sV); insV(c.y, sV); insV(c.z, sV); insV(c.w, sV); insV(b.y, sV);
        cntf += b.z;
    }

#pragma unroll
    for (int off = 1; off <= 4; off <<= 1) {
        float bv[5];
#pragma unroll
        for (int i = 0; i < 5; ++i) bv[i] = __shfl_xor(dV[i], off);
#pragma unroll
        for (int i = 0; i < 5; ++i) insV(bv[i], dV);
#pragma unroll
        for (int i = 0; i < 5; ++i) bv[i] = __shfl_xor(sV[i], off);
#pragma unroll
        for (int i = 0; i < 5; ++i) insV(bv[i], sV);
        cntf += __shfl_xor(cntf, off);
    }

    float res = 0.f;
    if (part == 0) {
        const float nR = norms[r];
        const int pos = (int)cntf;
        const int ks = (pos < 5) ? pos : 5;
        float dS[5], sS[5];
#pragma unroll
        for (int i = 0; i < 5; ++i) {
            float dv = dV[i]; bool ok = dv < 1e29f;
            dS[i] = ok ? (-sqrtf(fmaxf(nR + dv, 0.f)) + MARGINF) : NEGV;
        }
#pragma unroll
        for (int i = 0; i < 5; ++i) {
            float sv = sV[i]; bool ok = sv < 1e29f;
            sS[i] = ok ? -sqrtf(fmaxf(nR + sv, 0.f)) : NEGV;
        }
        float mV[5]; int mF[5];
#pragma unroll
        for (int i = 0; i < 5; ++i) { mV[i] = dS[i]; mF[i] = 0; }
#pragma unroll
        for (int i = 0; i < 5; ++i) insDF(sS[i], 1, mV, mF);

        float fpsum = 0.f; int fpn = 0;
#pragma unroll
        for (int i = 0; i < 5; ++i)
            if (i < ks && mF[i] == 0) { fpsum += mV[i]; fpn++; }
        const int s0 = ks - fpn;
        float fnsum = 0.f;
#pragma unroll
        for (int i = 0; i < 5; ++i)
            if (i >= s0 && i < s0 + fpn) fnsum += sS[i];
        res = fpsum - fnsum;
    }
    sh[t] = res;
    __syncthreads();
    for (int s = 128; s > 0; s >>= 1) {
        if (t < s) sh[t] += sh[t + s];
        __syncthreads();
    }
    if (t == 0) {
        partials[bx] = sh[0];
        __threadfence();
        int old = atomicAdd(ticket, 1);
        lastFlag = (old == (int)gridDim.x - 1) ? 1 : 0;
    }
    __syncthreads();
    if (lastFlag) {
        __threadfence();
        float v = (t < 128) ? partials[t] : 0.f;
        sh[t] = v;
        __syncthreads();
        for (int s = 128; s > 0; s >>= 1) {
            if (t < s) sh[t] += sh[t + s];
            __syncthreads();
        }
        if (t == 0) out[0] = sh[0];
    }
}

extern "C" void kernel_launch(void* const* d_in, const int* in_sizes, int n_in,
                              void* d_out, int out_size, void* d_ws, size_t ws_size,
                              hipStream_t stream) {
    const float* X      = (const float*)d_in[0];
    const int*   labels = (const int*)d_in[1];

    float* ws       = (float*)d_ws;
    float* norms    = ws;                          // 4096 f32
    float* partials = ws + BS;                     // 128 f32
    int*   ticket   = (int*)(ws + BS + 128);       // 1 i32 (+pad to 16)
    float* lists    = ws + BS + 128 + 16;          // 4096*32*12 f32 = 6.29 MB
    unsigned short* Xp = (unsigned short*)(lists + (size_t)BS * NS * LSTR); // 1 MB

    prep_kernel<<<BS / 32, 256, 0, stream>>>(X, norms, Xp, ticket);
    main_kernel<<<(BS / 64) * NS, 256, 0, stream>>>(Xp, labels, norms, lists);
    merge_kernel<<<(BS * 8) / 256, 256, 0, stream>>>(lists, labels, norms,
                                                     partials, ticket, (float*)d_out);
}

// Round 10
// 39.157 us; speedup vs baseline: 1.7053x; 1.0916x over previous
//
#include <hip/hip_runtime.h>
#include <math.h>

#define BS 4096
#define D 128
#define NS 32          // column slices
#define SC 128         // cols per slice
#define MARGINF 0.1f
#define NEGV -1e30f
#define BIGD 1e30f
#define LSTR 12        // record: dV[0..3]@0, {dV4,sV4,cnt,pad}@4, sV[0..3]@8

typedef float f32x4 __attribute__((ext_vector_type(4)));
typedef short s16x8 __attribute__((ext_vector_type(8)));

#define GLD_LDS16(gsrc, ldst) __builtin_amdgcn_global_load_lds( \
    (const __attribute__((address_space(1))) unsigned int*)(const void*)(gsrc), \
    (__attribute__((address_space(3))) unsigned int*)(void*)(ldst), 16, 0, 0)

__device__ __forceinline__ unsigned short f2bf(float f) {
    unsigned int u = __float_as_uint(f);
    unsigned int r = u + 0x7FFFu + ((u >> 16) & 1u);
    return (unsigned short)(r >> 16);
}

// sorted-ascending top-5 insert via med3: W[0]=min(V0,v), W[t]=med3(V[t-1],V[t],v).
// 5 INDEPENDENT ops (v_min + 4x v_med3) -- no serial chain within the insert.
__device__ __forceinline__ void insV(float v, float (&V)[5]) {
    float w0 = fminf(V[0], v);
    float w1 = __builtin_amdgcn_fmed3f(V[0], V[1], v);
    float w2 = __builtin_amdgcn_fmed3f(V[1], V[2], v);
    float w3 = __builtin_amdgcn_fmed3f(V[2], V[3], v);
    float w4 = __builtin_amdgcn_fmed3f(V[3], V[4], v);
    V[0] = w0; V[1] = w1; V[2] = w2; V[3] = w3; V[4] = w4;
}

// descending insert with same-class flag payload (epilogue only, 5 uses/row)
__device__ __forceinline__ void insDF(float v, int f, float (&V)[5], int (&F)[5]) {
#pragma unroll
    for (int t = 0; t < 5; ++t) {
        bool c = v > V[t];
        float tv = V[t]; int tf = F[t];
        V[t] = c ? v : tv; F[t] = c ? f : tf;
        v = c ? tv : v;    f = c ? tf : f;
    }
}

// norms + fragment-tiled bf16 copy of X (LDS-staged transpose, both global
// sides coalesced; LDS XOR-swizzled 16B chunks => <=2-way banks). Also zeroes
// the merge ticket (visible to merge via dispatch ordering on the stream).
// Xp layout: row group g=row>>4, k-chunk ks, lane l2=(q*16+rl):
//   byte off = g*4096 + ks*1024 + l2*16 holds row (16g+rl), k [ks*32+q*8, +8)
__global__ __launch_bounds__(256) void prep_kernel(
        const float* __restrict__ X, float* __restrict__ norms,
        unsigned short* __restrict__ Xp, int* __restrict__ ticket) {
    __shared__ __align__(16) unsigned short sb[32 * 128];   // 8 KB
    const int t = threadIdx.x, bx = blockIdx.x;
    const int row0 = bx * 32;

    if (bx == 0 && t == 0) ticket[0] = 0;

#pragma unroll
    for (int i = 0; i < 4; ++i) {
        int idx = i * 256 + t;                 // float4 units 0..1023
        int lr = idx >> 5, kq = idx & 31;
        float4 v = ((const float4*)X)[(size_t)row0 * 32 + idx];
        float acc = v.x * v.x + v.y * v.y + v.z * v.z + v.w * v.w;
#pragma unroll
        for (int off = 1; off < 32; off <<= 1) acc += __shfl_xor(acc, off);
        if (kq == 0) norms[row0 + lr] = acc;
        ushort4 hv = { f2bf(v.x), f2bf(v.y), f2bf(v.z), f2bf(v.w) };
        int chunk = (kq >> 1) ^ (lr & 7);
        *(ushort4*)((char*)sb + lr * 256 + (chunk << 4) + (kq & 1) * 8) = hv;
    }
    __syncthreads();

#pragma unroll
    for (int i = 0; i < 2; ++i) {
        int u = i * 256 + t;                   // 16B units 0..511
        int j = u >> 8, ug = u & 255;
        int ks = ug >> 6, l2 = ug & 63;
        int lr = j * 16 + (l2 & 15), q = l2 >> 4;
        int chunk = (ks * 4 + q) ^ (lr & 7);
        ulonglong2 d = *(const ulonglong2*)((const char*)sb + lr * 256 + (chunk << 4));
        *(ulonglong2*)((char*)Xp + (size_t)(bx * 2 + j) * 4096 + ks * 1024 + l2 * 16) = d;
    }
}

// wave = 16 rows x 128 cols (one slice). Slice col-panel (32KB) staged ONCE
// per block into LDS via global_load_lds (linear dest; Xp is already in lane
// order), then conflict-free ds_read_b128 fragments. Swapped MFMA: lane
// (rl=l&15, q=l>>4) holds cols {i*16+q*4+e} of row rl. Values-only top-5
// lists in d2' = nC - 2s space; same-class count per slice.
__global__ __launch_bounds__(256, 5) void main_kernel(
        const unsigned short* __restrict__ Xp, const int* __restrict__ labels,
        const float* __restrict__ norms, float* __restrict__ lists) {
    __shared__ __align__(16) char shA[32768];   // 8 col-groups x 4KB
    const int t = threadIdx.x, bx = blockIdx.x;
    const int slice = bx & (NS - 1);
    const int col0 = slice * SC;
    const int w = t >> 6, l = t & 63, rl = l & 15, q = l >> 4;
    const int gRow = (bx >> 5) * 4 + w;
    const int rowG = gRow * 16 + rl;
    const int lR = labels[rowG];
    const char* Pb = (const char*)Xp;

    // stage: wave w issues chunks [8w, 8w+8): 1KB each, LDS dest = base + lane*16
#pragma unroll
    for (int c = 0; c < 8; ++c) {
        int chunk = w * 8 + c;                 // chunk = grp*4 + ks
        const char* src = Pb + (size_t)(slice * 8 + (chunk >> 2)) * 4096
                             + (chunk & 3) * 1024 + l * 16;
        GLD_LDS16(src, shA + chunk * 1024);
    }

    s16x8 brow[4];
#pragma unroll
    for (int ks = 0; ks < 4; ++ks)
        brow[ks] = *(const s16x8*)(Pb + (size_t)gRow * 4096 + ks * 1024 + l * 16);

    __syncthreads();   // drains vmcnt (global_load_lds + brow) before use

    f32x4 acc[8];
#pragma unroll
    for (int i = 0; i < 8; ++i) acc[i] = (f32x4){0.f, 0.f, 0.f, 0.f};

#pragma unroll
    for (int ks = 0; ks < 4; ++ks) {
        s16x8 af[8];
#pragma unroll
        for (int i = 0; i < 8; ++i)
            af[i] = *(const s16x8*)(shA + i * 4096 + ks * 1024 + l * 16);
#pragma unroll
        for (int i = 0; i < 8; ++i)
            acc[i] = __builtin_amdgcn_mfma_f32_16x16x32_bf16(af[i], brow[ks], acc[i], 0, 0, 0);
    }

    float dV[5], sV[5];
#pragma unroll
    for (int i = 0; i < 5; ++i) { dV[i] = BIGD; sV[i] = BIGD; }
    int cnt = 0;

#pragma unroll
    for (int i = 0; i < 8; ++i) {
        f32x4 nc4 = *(const f32x4*)(norms + col0 + i * 16 + q * 4);
        int4  lc4 = *(const int4*)(labels + col0 + i * 16 + q * 4);
        int lcv[4] = {lc4.x, lc4.y, lc4.z, lc4.w};
#pragma unroll
        for (int e = 0; e < 4; ++e) {
            float v = fmaf(acc[i][e], -2.f, nc4[e]);   // d2' = nC - 2s (nR added at merge)
            bool same = (lcv[e] == lR);
            cnt += same ? 1 : 0;
            insV(same ? BIGD : v, dV);
            if (__any(same)) insV(same ? v : BIGD, sV);
        }
    }

    // merge the 4 col-quarters of each row (lanes l, l^16, l^32, l^48)
#pragma unroll
    for (int off = 16; off <= 32; off <<= 1) {
        float bv[5];
#pragma unroll
        for (int i = 0; i < 5; ++i) bv[i] = __shfl_xor(dV[i], off);
#pragma unroll
        for (int i = 0; i < 5; ++i) insV(bv[i], dV);
#pragma unroll
        for (int i = 0; i < 5; ++i) bv[i] = __shfl_xor(sV[i], off);
#pragma unroll
        for (int i = 0; i < 5; ++i) insV(bv[i], sV);
        cnt += __shfl_xor(cnt, off);
    }

    if (q == 0) {
        float* Lp = lists + ((size_t)rowG * NS + slice) * LSTR;
        *(f32x4*)Lp       = (f32x4){dV[0], dV[1], dV[2], dV[3]};
        *(f32x4*)(Lp + 4) = (f32x4){dV[4], sV[4], (float)cnt, 0.f};
        *(f32x4*)(Lp + 8) = (f32x4){sV[0], sV[1], sV[2], sV[3]};
    }
}

// 16 threads per row: thread part owns slices {2*part, 2*part+1}.
// shfl-merge xor 1,2,4,8; epilogue on part==0; block partial; last block
// (ticket) parallel-sums the 256 partials in fixed order -> out.
__global__ __launch_bounds__(256) void merge_kernel(
        const float* __restrict__ lists, const int* __restrict__ labels,
        const float* __restrict__ norms, float* __restrict__ partials,
        int* __restrict__ ticket, float* __restrict__ out) {
    __shared__ float sh[256];
    __shared__ int lastFlag;
    const int t = threadIdx.x, bx = blockIdx.x;
    const int gid = bx * 256 + t;
    const int r = gid >> 4, part = gid & 15;

    float dV[5], sV[5];
#pragma unroll
    for (int i = 0; i < 5; ++i) { dV[i] = BIGD; sV[i] = BIGD; }
    float cntf = 0.f;
#pragma unroll
    for (int s = 0; s < 2; ++s) {
        const float* rec = lists + (size_t)(r * NS + part * 2 + s) * LSTR;
        f32x4 a = *(const f32x4*)rec;
        f32x4 b = *(const f32x4*)(rec + 4);
        f32x4 c = *(const f32x4*)(rec + 8);
        insV(a.x, dV); insV(a.y, dV); insV(a.z, dV); insV(a.w, dV); insV(b.x, dV);
        insV(c.x, sV); insV(c.y, sV); insV(c.z, sV); insV(c.w, sV); insV(b.y, sV);
        cntf += b.z;
    }

#pragma unroll
    for (int off = 1; off <= 8; off <<= 1) {
        float bv[5];
#pragma unroll
        for (int i = 0; i < 5; ++i) bv[i] = __shfl_xor(dV[i], off);
#pragma unroll
        for (int i = 0; i < 5; ++i) insV(bv[i], dV);
#pragma unroll
        for (int i = 0; i < 5; ++i) bv[i] = __shfl_xor(sV[i], off);
#pragma unroll
        for (int i = 0; i < 5; ++i) insV(bv[i], sV);
        cntf += __shfl_xor(cntf, off);
    }

    float res = 0.f;
    if (part == 0) {
        const float nR = norms[r];
        const int pos = (int)cntf;
        const int ks = (pos < 5) ? pos : 5;
        float dS[5], sS[5];
#pragma unroll
        for (int i = 0; i < 5; ++i) {
            float dv = dV[i]; bool ok = dv < 1e29f;
            dS[i] = ok ? (-sqrtf(fmaxf(nR + dv, 0.f)) + MARGINF) : NEGV;
        }
#pragma unroll
        for (int i = 0; i < 5; ++i) {
            float sv = sV[i]; bool ok = sv < 1e29f;
            sS[i] = ok ? -sqrtf(fmaxf(nR + sv, 0.f)) : NEGV;
        }
        float mV[5]; int mF[5];
#pragma unroll
        for (int i = 0; i < 5; ++i) { mV[i] = dS[i]; mF[i] = 0; }
#pragma unroll
        for (int i = 0; i < 5; ++i) insDF(sS[i], 1, mV, mF);

        float fpsum = 0.f; int fpn = 0;
#pragma unroll
        for (int i = 0; i < 5; ++i)
            if (i < ks && mF[i] == 0) { fpsum += mV[i]; fpn++; }
        const int s0 = ks - fpn;
        float fnsum = 0.f;
#pragma unroll
        for (int i = 0; i < 5; ++i)
            if (i >= s0 && i < s0 + fpn) fnsum += sS[i];
        res = fpsum - fnsum;
    }
    sh[t] = res;
    __syncthreads();
    for (int s = 128; s > 0; s >>= 1) {
        if (t < s) sh[t] += sh[t + s];
        __syncthreads();
    }
    if (t == 0) {
        partials[bx] = sh[0];
        __threadfence();
        int old = atomicAdd(ticket, 1);
        lastFlag = (old == (int)gridDim.x - 1) ? 1 : 0;
    }
    __syncthreads();
    if (lastFlag) {
        __threadfence();
        sh[t] = partials[t];               // gridDim.x == 256
        __syncthreads();
        for (int s = 128; s > 0; s >>= 1) {
            if (t < s) sh[t] += sh[t + s];
            __syncthreads();
        }
        if (t == 0) out[0] = sh[0];
    }
}

extern "C" void kernel_launch(void* const* d_in, const int* in_sizes, int n_in,
                              void* d_out, int out_size, void* d_ws, size_t ws_size,
                              hipStream_t stream) {
    const float* X      = (const float*)d_in[0];
    const int*   labels = (const int*)d_in[1];

    float* ws       = (float*)d_ws;
    float* norms    = ws;                          // 4096 f32
    float* partials = ws + BS;                     // 256 f32
    int*   ticket   = (int*)(ws + BS + 256);       // 1 i32 (+pad to 16)
    float* lists    = ws + BS + 256 + 16;          // 4096*32*12 f32 = 6.29 MB
    unsigned short* Xp = (unsigned short*)(lists + (size_t)BS * NS * LSTR); // 1 MB

    prep_kernel<<<BS / 32, 256, 0, stream>>>(X, norms, Xp, ticket);
    main_kernel<<<(BS / 64) * NS, 256, 0, stream>>>(Xp, labels, norms, lists);
    merge_kernel<<<(BS * 16) / 256, 256, 0, stream>>>(lists, labels, norms,
                                                      partials, ticket, (float*)d_out);
}